// Round 6
// baseline (196.067 us; speedup 1.0000x reference)
//
#include <hip/hip_runtime.h>
#include <math.h>

#define C_ 100
#define K_ 8
#define D_ 64
#define B_ 2048

using f16x8 = __attribute__((ext_vector_type(8))) _Float16;
using f32x4 = __attribute__((ext_vector_type(4))) float;

// DPP-based cross-lane add within each 16-lane group.
template <int CTRL>
__device__ __forceinline__ float dpp_xadd(float x) {
    int v = __builtin_amdgcn_update_dpp(0, __float_as_int(x), CTRL, 0xf, 0xf, true);
    return x + __int_as_float(v);
}
__device__ __forceinline__ float sum16(float x) {
    x = dpp_xadd<0xB1>(x);   // quad_perm xor1
    x = dpp_xadd<0x4E>(x);   // quad_perm xor2
    x = dpp_xadd<0x141>(x);  // row_half_mirror ≡ xor4
    x = dpp_xadd<0x140>(x);  // row_mirror ≡ xor8
    return x;
}

// ---------------- fused kernel: invert + MFMA GEMM + quad + LSE over K --------------
// block: 512 thr (8 waves) = one class c x 256 b-rows. Wave w owns component k=w:
//  A) register-resident inversion of unit-lower-triangular L (L rows read as
//     wave-uniform global broadcasts), transpose to MFMA B-fragments via a per-wave
//     4KB LDS slice (2 rounds, no barrier), v = A_f16*mu in registers.
//  B) X tile staged f32->f16 into xor-swizzled LDS (reuses slice region), MFMA s-loop
//     with acc initialized to -v, quad via dpp sum16, deferred LSE, coalesced clp.
// LDS = 32768 (slices/Xs) + 8192 (qk) = 40960 -> 4 blocks/CU.
__global__ __launch_bounds__(512, 4) void k_all(const float* __restrict__ rep,
                                                const float* __restrict__ ml,
                                                const float* __restrict__ loc_g,
                                                const float* __restrict__ L_g,
                                                float* __restrict__ clp_g) {
    const int c = blockIdx.y;
    const int b0 = blockIdx.x * 256;
    const int tid = threadIdx.x;
    const int w = tid >> 6;        // wave = component k
    const int lane = tid & 63;
    const int col = lane & 15;
    const int quad = lane >> 4;

    __shared__ __align__(16) char smem[40960];

    // ---- phase A: inversion (thread j owns column j of A = L^-1) ----
    const int ck = c * K_ + w;
    const float* Lbase = L_g + (size_t)ck * D_ * D_;
    const int j = lane;

    float a[D_];
#pragma unroll
    for (int m = 0; m < D_; ++m) a[m] = (j == m) ? 1.f : 0.f;

#pragma unroll
    for (int i = 1; i < D_; ++i) {
        const float* Lrow = Lbase + i * D_;   // wave-uniform address -> broadcast
        float a0 = 0.f, a1 = 0.f, a2 = 0.f, a3 = 0.f;
#pragma unroll
        for (int m0 = 0; m0 + 3 < i; m0 += 4) {
            const float4 L4 = *reinterpret_cast<const float4*>(Lrow + m0);
            a0 = fmaf(L4.x, a[m0 + 0], a0);
            a1 = fmaf(L4.y, a[m0 + 1], a1);
            a2 = fmaf(L4.z, a[m0 + 2], a2);
            a3 = fmaf(L4.w, a[m0 + 3], a3);
        }
#pragma unroll
        for (int m = i & ~3; m < i; ++m) a0 = fmaf(Lrow[m], a[m], a0);
        const float nv = -((a0 + a1) + (a2 + a3));   // unit diagonal: no divide
        a[i] = (j < i) ? nv : a[i];
    }

    // ---- transpose to B-fragments via per-wave 4KB slice, 2 rounds ----
    // value a[r]=A[r][j] -> frag f=(r>>4)*2+(j>>5), lane l=((j>>3)&3)*16|(r&15), s=j&7
    _Float16* sl = (_Float16*)(smem + w * 4096);
    const int ks_ = j >> 5, ssub = j & 7, lgrp = (j >> 3) & 3;
    f16x8 Bf[8];
#pragma unroll
    for (int rr = 0; rr < 2; ++rr) {
#pragma unroll
        for (int r = rr * 32; r < rr * 32 + 32; ++r) {
            const int floc = ((r >> 4) & 1) * 2 + ks_;
            const int l = lgrp * 16 + (r & 15);
            sl[floc * 512 + l * 8 + ssub] = (_Float16)a[r];
        }
        // same-wave LDS RAW: compiler inserts lgkmcnt wait
#pragma unroll
        for (int f = 0; f < 4; ++f)
            Bf[rr * 4 + f] = reinterpret_cast<const f16x8*>(sl)[f * 64 + lane];
    }

    // ---- v[d] = sum_j A_f16[d][j] * mu[j]; lane ends with vv[dt] for d=dt*16+col ----
    const float* mu = loc_g + (size_t)ck * D_;
    float muv[16];
#pragma unroll
    for (int s = 0; s < 8; ++s) {
        muv[s] = mu[quad * 8 + s];
        muv[8 + s] = mu[32 + quad * 8 + s];
    }
    float vv[4];
#pragma unroll
    for (int dt = 0; dt < 4; ++dt) {
        float vp = 0.f;
#pragma unroll
        for (int ks = 0; ks < 2; ++ks)
#pragma unroll
            for (int s = 0; s < 8; ++s)
                vp = fmaf((float)Bf[dt * 2 + ks][s], muv[ks * 8 + s], vp);
        vp += __shfl_xor(vp, 16, 64);
        vp += __shfl_xor(vp, 32, 64);
        vv[dt] = vp;
    }
    __syncthreads();   // slices dead; region becomes Xs

    // ---- phase B: stage X tile f32 -> f16, xor-swizzled ----
    f16x8* Xs = (f16x8*)smem;
    float* qk = (float*)(smem + 32768);
#pragma unroll
    for (int p = 0; p < 4; ++p) {
        const int u = p * 512 + tid;
        const int q = u & 7, row = u >> 3;
        const float* xr = rep + (size_t)(b0 + row) * D_ + q * 8;
        f16x8 val;
#pragma unroll
        for (int e = 0; e < 8; ++e) val[e] = (_Float16)xr[e];
        const int s = row >> 5, bt = (row >> 4) & 1, cc = row & 15;
        Xs[((s * 2 + bt) * 8 + q) * 16 + (q ^ cc)] = val;
    }
    __syncthreads();

    // ---- MFMA s-loop over 8 x 32-row subtiles ----
    for (int s = 0; s < 8; ++s) {
        f16x8 Xf[2][2];
#pragma unroll
        for (int bt = 0; bt < 2; ++bt)
#pragma unroll
            for (int ks = 0; ks < 2; ++ks) {
                const int q = ks * 4 + quad;
                Xf[bt][ks] = Xs[((s * 2 + bt) * 8 + q) * 16 + (q ^ col)];
            }

        f32x4 acc[2][4];
#pragma unroll
        for (int bt = 0; bt < 2; ++bt)
#pragma unroll
            for (int dt = 0; dt < 4; ++dt) {
                const f32x4 ini = {-vv[dt], -vv[dt], -vv[dt], -vv[dt]};
                acc[bt][dt] = __builtin_amdgcn_mfma_f32_16x16x32_f16(
                    Xf[bt][0], Bf[dt * 2 + 0], ini, 0, 0, 0);
                acc[bt][dt] = __builtin_amdgcn_mfma_f32_16x16x32_f16(
                    Xf[bt][1], Bf[dt * 2 + 1], acc[bt][dt], 0, 0, 0);
            }

#pragma unroll
        for (int bt = 0; bt < 2; ++bt) {
            float p[4];
#pragma unroll
            for (int r = 0; r < 4; ++r) {
                float sum = 0.f;
#pragma unroll
                for (int dt = 0; dt < 4; ++dt) {
                    const float y = acc[bt][dt][r];   // already z - v
                    sum = fmaf(y, y, sum);
                }
                p[r] = sum;
            }
#pragma unroll
            for (int r = 0; r < 4; ++r) p[r] = sum16(p[r]);
            if (col == 0) {
                f32x4 pv = {p[0], p[1], p[2], p[3]};
                *reinterpret_cast<f32x4*>(
                    &qk[w * 256 + s * 32 + bt * 16 + quad * 4]) = pv;
            }
        }
    }
    __syncthreads();

    // ---- deferred LSE over k (logdet == 0: unit diagonal by construction) ----
    if (tid < 256) {
        float mlv[K_];
        float mx = -INFINITY;
#pragma unroll
        for (int k = 0; k < K_; ++k) { mlv[k] = ml[c * K_ + k]; mx = fmaxf(mx, mlv[k]); }
        float se = 0.f;
#pragma unroll
        for (int k = 0; k < K_; ++k) se += __expf(mlv[k] - mx);
        const float lse = mx + __logf(se);

        float lp[K_];
        float m2 = -INFINITY;
#pragma unroll
        for (int k = 0; k < K_; ++k) {
            lp[k] = (mlv[k] - lse - 58.8120661251f) - 0.5f * qk[k * 256 + tid];
            m2 = fmaxf(m2, lp[k]);
        }
        float s2 = 0.f;
#pragma unroll
        for (int k = 0; k < K_; ++k) s2 += __expf(lp[k] - m2);
        clp_g[(size_t)c * B_ + b0 + tid] = m2 + __logf(s2);
    }
}

// ---------------- kernel 2: log_softmax over C per batch row -------------------------
// clp layout is [C][B]; lane = class index.
__global__ __launch_bounds__(256) void k_final(const float* __restrict__ clp,
                                               float* __restrict__ out) {
    const int wave = threadIdx.x >> 6;
    const int lane = threadIdx.x & 63;
    const int b = blockIdx.x * 4 + wave;
    const float x0 = clp[(size_t)lane * B_ + b];
    const float x1 = (lane < C_ - 64) ? clp[(size_t)(64 + lane) * B_ + b] : -INFINITY;
    float m = fmaxf(x0, x1);
    for (int o = 32; o > 0; o >>= 1) m = fmaxf(m, __shfl_xor(m, o, 64));
    float s = __expf(x0 - m) + ((lane < C_ - 64) ? __expf(x1 - m) : 0.f);
    for (int o = 32; o > 0; o >>= 1) s += __shfl_xor(s, o, 64);
    const float L = m + __logf(s);
    out[(size_t)b * C_ + lane] = x0 - L;
    if (lane < C_ - 64) out[(size_t)b * C_ + 64 + lane] = x1 - L;
}

extern "C" void kernel_launch(void* const* d_in, const int* in_sizes, int n_in,
                              void* d_out, int out_size, void* d_ws, size_t ws_size,
                              hipStream_t stream) {
    const float* rep = (const float*)d_in[0];        // [B, D]
    const float* ml  = (const float*)d_in[1];        // [C, K]
    const float* loc = (const float*)d_in[2];        // [C, K, D]
    const float* st  = (const float*)d_in[3];        // [C, K, D, D]
    float* out = (float*)d_out;                      // [B, C]

    float* clp = (float*)d_ws;                       // [C][B] = 819,200 B

    k_all<<<dim3(B_ / 256, C_), dim3(512), 0, stream>>>(rep, ml, loc, st, clp);
    k_final<<<dim3(B_ / 4), dim3(256), 0, stream>>>(clp, out);
}

// Round 7
// 110.974 us; speedup vs baseline: 1.7668x; 1.7668x over previous
//
#include <hip/hip_runtime.h>
#include <math.h>

#define C_ 100
#define K_ 8
#define D_ 64
#define B_ 2048

using f16x8 = __attribute__((ext_vector_type(8))) _Float16;
using f32x4 = __attribute__((ext_vector_type(4))) float;

// DPP-based cross-lane add within each 16-lane group.
template <int CTRL>
__device__ __forceinline__ float dpp_xadd(float x) {
    int v = __builtin_amdgcn_update_dpp(0, __float_as_int(x), CTRL, 0xf, 0xf, true);
    return x + __int_as_float(v);
}
__device__ __forceinline__ float sum16(float x) {
    x = dpp_xadd<0xB1>(x);   // quad_perm xor1
    x = dpp_xadd<0x4E>(x);   // quad_perm xor2
    x = dpp_xadd<0x141>(x);  // row_half_mirror ≡ xor4
    x = dpp_xadd<0x140>(x);  // row_mirror ≡ xor8
    return x;
}

// ---------------- kernel 1: invert unit-lower-triangular L per (c,k) ----------------
// Register-resident substitution (needs ~132 VGPR -> MUST stay its own kernel;
// fusing under an occupancy-bound launch spills a[64] to scratch — R6 regression).
#define LS_S 68
#define AT_S 65
__global__ __launch_bounds__(64, 1) void k_invert(const float* __restrict__ L_g,
                                                  const float* __restrict__ rep,
                                                  const float* __restrict__ loc_g,
                                                  f16x8* __restrict__ ATf,
                                                  _Float16* __restrict__ Xh,
                                                  float* __restrict__ v_g,
                                                  float* __restrict__ ld_g) {
    const int ck = blockIdx.x;
    const int j = threadIdx.x;
    __shared__ float Ls[D_][LS_S];
    __shared__ float At[D_][AT_S];
    __shared__ float mus[D_];

    for (int idx = ck * 64 + j; idx < B_ * D_; idx += C_ * K_ * 64)
        Xh[idx] = (_Float16)rep[idx];

    const float* Lsrc = L_g + (size_t)ck * D_ * D_;
#pragma unroll
    for (int t = 0; t < D_; ++t)
        Ls[t][j] = Lsrc[t * D_ + j];
    mus[j] = loc_g[ck * D_ + j];
    __syncthreads();

    {
        float ll = __logf(fabsf(Ls[j][j]));
        ll = sum16(ll);
        ll += __shfl_xor(ll, 16, 64);
        ll += __shfl_xor(ll, 32, 64);
        if (j == 0) ld_g[ck] = ll;
    }

    float a[D_];
    const float r0 = __builtin_amdgcn_rcpf(Ls[j][j]);
#pragma unroll
    for (int m = 0; m < D_; ++m) a[m] = (j == m) ? r0 : 0.f;

#pragma unroll
    for (int i = 1; i < D_; ++i) {
        float a0 = 0.f, a1 = 0.f, a2 = 0.f, a3 = 0.f;
#pragma unroll
        for (int m0 = 0; m0 + 3 < i; m0 += 4) {
            const float4 L4 = *reinterpret_cast<const float4*>(&Ls[i][m0]);
            a0 = fmaf(L4.x, a[m0 + 0], a0);
            a1 = fmaf(L4.y, a[m0 + 1], a1);
            a2 = fmaf(L4.z, a[m0 + 2], a2);
            a3 = fmaf(L4.w, a[m0 + 3], a3);
        }
#pragma unroll
        for (int m = i & ~3; m < i; ++m) a0 = fmaf(Ls[i][m], a[m], a0);
        const float acc = (a0 + a1) + (a2 + a3);
        const float nv = -acc * __builtin_amdgcn_rcpf(Ls[i][i]);
        a[i] = (j < i) ? nv : a[i];
    }

#pragma unroll
    for (int m = 0; m < D_; ++m) At[m][j] = a[m];
    __syncthreads();

    const int q8 = (j >> 4) * 8, cl = j & 15;
    float vpart[4];
#pragma unroll
    for (int dt = 0; dt < 4; ++dt) {
        vpart[dt] = 0.f;
#pragma unroll
        for (int ks = 0; ks < 2; ++ks) {
            f16x8 t;
#pragma unroll
            for (int s = 0; s < 8; ++s) {
                const _Float16 h = (_Float16)At[dt * 16 + cl][ks * 32 + q8 + s];
                t[s] = h;
                vpart[dt] = fmaf((float)h, mus[ks * 32 + q8 + s], vpart[dt]);
            }
            ATf[(size_t)ck * 512 + (dt * 2 + ks) * 64 + j] = t;
        }
        vpart[dt] += __shfl_xor(vpart[dt], 16, 64);
        vpart[dt] += __shfl_xor(vpart[dt], 32, 64);
    }
    if (j < 16) {
#pragma unroll
        for (int dt = 0; dt < 4; ++dt)
            v_g[(size_t)ck * D_ + dt * 16 + j] = vpart[dt];
    }
}

// ---------------- kernel 2: MFMA GEMM, wave-per-component --------------------------
// block: 512 thr (8 waves) = one class c x 256 b-rows; wave w owns component k=w.
// s-loop kept ROLLED (#pragma unroll 1) to keep the hot body I-cache-resident.
// -v folded into the MFMA C-operand init.
__global__ __launch_bounds__(512, 4) void k_main(const _Float16* __restrict__ Xh,
                                                 const f16x8* __restrict__ ATf,
                                                 const float* __restrict__ v_g,
                                                 const float* __restrict__ ml,
                                                 const float* __restrict__ ld_g,
                                                 float* __restrict__ clp_g) {
    const int c = blockIdx.y;
    const int b0 = blockIdx.x * 256;
    const int tid = threadIdx.x;
    const int w = tid >> 6;        // wave = component k
    const int lane = tid & 63;
    const int col = lane & 15;
    const int quad = lane >> 4;

    __shared__ f16x8 Xs[2048];       // 32 KB
    __shared__ float qk[K_][260];    // quad results, padded
    __shared__ float offs_s[K_];

    const int ck = c * K_ + w;
    f16x8 Bf[8];
#pragma unroll
    for (int f = 0; f < 8; ++f)
        Bf[f] = ATf[(size_t)ck * 512 + f * 64 + lane];
    float vv[4];
#pragma unroll
    for (int dt = 0; dt < 4; ++dt)
        vv[dt] = v_g[(size_t)ck * D_ + dt * 16 + col];

    if (tid < K_) {
        float vals[K_];
        float mx = -INFINITY;
#pragma unroll
        for (int k = 0; k < K_; ++k) { vals[k] = ml[c * K_ + k]; mx = fmaxf(mx, vals[k]); }
        float s = 0.f;
#pragma unroll
        for (int k = 0; k < K_; ++k) s += __expf(vals[k] - mx);
        const float lse = mx + __logf(s);
        offs_s[tid] = vals[tid] - lse - 58.8120661251f - ld_g[c * K_ + tid];
    }

    // stage X tile: coalesced global reads, xor-swizzled LDS chunk writes.
#pragma unroll
    for (int p = 0; p < 4; ++p) {
        const int u = p * 512 + tid;
        const int q = u & 7, row = u >> 3;
        const f16x8 val = *reinterpret_cast<const f16x8*>(
            Xh + (size_t)(b0 + row) * D_ + q * 8);
        const int s = row >> 5, bt = (row >> 4) & 1, cc = row & 15;
        Xs[((s * 2 + bt) * 8 + q) * 16 + (q ^ cc)] = val;
    }
    __syncthreads();

#pragma unroll 1
    for (int s = 0; s < 8; ++s) {
        f16x8 Xf[2][2];
#pragma unroll
        for (int bt = 0; bt < 2; ++bt)
#pragma unroll
            for (int ks = 0; ks < 2; ++ks) {
                const int q = ks * 4 + quad;
                Xf[bt][ks] = Xs[((s * 2 + bt) * 8 + q) * 16 + (q ^ col)];
            }

        f32x4 acc[2][4];
#pragma unroll
        for (int bt = 0; bt < 2; ++bt)
#pragma unroll
            for (int dt = 0; dt < 4; ++dt) {
                const f32x4 ini = {-vv[dt], -vv[dt], -vv[dt], -vv[dt]};
                acc[bt][dt] = __builtin_amdgcn_mfma_f32_16x16x32_f16(
                    Xf[bt][0], Bf[dt * 2 + 0], ini, 0, 0, 0);
                acc[bt][dt] = __builtin_amdgcn_mfma_f32_16x16x32_f16(
                    Xf[bt][1], Bf[dt * 2 + 1], acc[bt][dt], 0, 0, 0);
            }

#pragma unroll
        for (int bt = 0; bt < 2; ++bt) {
            float p[4];
#pragma unroll
            for (int r = 0; r < 4; ++r) {
                float sum = 0.f;
#pragma unroll
                for (int dt = 0; dt < 4; ++dt) {
                    const float y = acc[bt][dt][r];   // already z - v
                    sum = fmaf(y, y, sum);
                }
                p[r] = sum;
            }
#pragma unroll
            for (int r = 0; r < 4; ++r) p[r] = sum16(p[r]);
            if (col == 0) {
                f32x4 pv = {p[0], p[1], p[2], p[3]};
                *reinterpret_cast<f32x4*>(&qk[w][s * 32 + bt * 16 + quad * 4]) = pv;
            }
        }
    }
    __syncthreads();

    if (tid < 256) {
        float lp[K_];
        float m = -INFINITY;
#pragma unroll
        for (int k = 0; k < K_; ++k) {
            lp[k] = fmaf(-0.5f, qk[k][tid], offs_s[k]);
            m = fmaxf(m, lp[k]);
        }
        float s = 0.f;
#pragma unroll
        for (int k = 0; k < K_; ++k) s += __expf(lp[k] - m);
        clp_g[(size_t)c * B_ + b0 + tid] = m + __logf(s);
    }
}

// ---------------- kernel 3: log_softmax over C per batch row -------------------------
__global__ __launch_bounds__(256) void k_final(const float* __restrict__ clp,
                                               float* __restrict__ out) {
    const int wave = threadIdx.x >> 6;
    const int lane = threadIdx.x & 63;
    const int b = blockIdx.x * 4 + wave;
    const float x0 = clp[(size_t)lane * B_ + b];
    const float x1 = (lane < C_ - 64) ? clp[(size_t)(64 + lane) * B_ + b] : -INFINITY;
    float m = fmaxf(x0, x1);
    for (int o = 32; o > 0; o >>= 1) m = fmaxf(m, __shfl_xor(m, o, 64));
    float s = __expf(x0 - m) + ((lane < C_ - 64) ? __expf(x1 - m) : 0.f);
    for (int o = 32; o > 0; o >>= 1) s += __shfl_xor(s, o, 64);
    const float L = m + __logf(s);
    out[(size_t)b * C_ + lane] = x0 - L;
    if (lane < C_ - 64) out[(size_t)b * C_ + 64 + lane] = x1 - L;
}

extern "C" void kernel_launch(void* const* d_in, const int* in_sizes, int n_in,
                              void* d_out, int out_size, void* d_ws, size_t ws_size,
                              hipStream_t stream) {
    const float* rep = (const float*)d_in[0];        // [B, D]
    const float* ml  = (const float*)d_in[1];        // [C, K]
    const float* loc = (const float*)d_in[2];        // [C, K, D]
    const float* st  = (const float*)d_in[3];        // [C, K, D, D]
    float* out = (float*)d_out;                      // [B, C]

    char* w = (char*)d_ws;
    f16x8*    ATf = (f16x8*)w;                        // 6,553,600 B
    _Float16* Xh  = (_Float16*)(w + 6553600);         // 262,144 B
    float*    v   = (float*)(w + 6815744);            // 204,800 B
    float*    ld  = (float*)(w + 7020544);            // 3,200 B
    float*    clp = (float*)(w + 7023744);            // 819,200 B  [C][B]

    k_invert<<<dim3(C_ * K_), dim3(64), 0, stream>>>(st, rep, loc, ATf, Xh, v, ld);
    k_main<<<dim3(B_ / 256, C_), dim3(512), 0, stream>>>(Xh, ATf, v, ml, ld, clp);
    k_final<<<dim3(B_ / 4), dim3(256), 0, stream>>>(clp, out);
}

// Round 8
// 102.578 us; speedup vs baseline: 1.9114x; 1.0818x over previous
//
#include <hip/hip_runtime.h>
#include <math.h>

#define C_ 100
#define K_ 8
#define D_ 64
#define B_ 2048

using f16x8 = __attribute__((ext_vector_type(8))) _Float16;
using f32x4 = __attribute__((ext_vector_type(4))) float;

// DPP-based cross-lane add within each 16-lane group.
template <int CTRL>
__device__ __forceinline__ float dpp_xadd(float x) {
    int v = __builtin_amdgcn_update_dpp(0, __float_as_int(x), CTRL, 0xf, 0xf, true);
    return x + __int_as_float(v);
}
__device__ __forceinline__ float sum16(float x) {
    x = dpp_xadd<0xB1>(x);   // quad_perm xor1
    x = dpp_xadd<0x4E>(x);   // quad_perm xor2
    x = dpp_xadd<0x141>(x);  // row_half_mirror ≡ xor4
    x = dpp_xadd<0x140>(x);  // row_mirror ≡ xor8
    return x;
}

// ---------------- kernel 1: invert unit-lower-triangular L per (c,k) ----------------
// Register-resident substitution (~132 VGPR -> must stay its own kernel; R6 proved
// fusing under an occupancy-bound launch spills a[64]). Unit diagonal by construction
// (tril(raw,-1)+eye): logdet==0, no divides. Also computes the per-(c,k) mixture
// offset here (8-lane shuffle LSE) so k_main has no serial preamble.
#define LS_S 68
#define AT_S 65
__global__ __launch_bounds__(64, 1) void k_invert(const float* __restrict__ L_g,
                                                  const float* __restrict__ rep,
                                                  const float* __restrict__ loc_g,
                                                  const float* __restrict__ ml,
                                                  f16x8* __restrict__ ATf,
                                                  _Float16* __restrict__ Xh,
                                                  float* __restrict__ v_g,
                                                  float* __restrict__ off_g) {
    const int ck = blockIdx.x;
    const int j = threadIdx.x;
    __shared__ float Ls[D_][LS_S];
    __shared__ float At[D_][AT_S];
    __shared__ float mus[D_];

    // cast X to fp16 (strided across all 800 blocks) — independent, coalesced
    for (int idx = ck * 64 + j; idx < B_ * D_; idx += C_ * K_ * 64)
        Xh[idx] = (_Float16)rep[idx];

    // per-(c,k) offset: off = ml[ck] - lse(ml[c,:]) - 0.5*D*log(2pi)
    {
        const int c8 = (ck >> 3) << 3;
        const float mlj = ml[c8 + (j & 7)];
        float mx = mlj;
        mx = fmaxf(mx, __shfl_xor(mx, 1, 64));
        mx = fmaxf(mx, __shfl_xor(mx, 2, 64));
        mx = fmaxf(mx, __shfl_xor(mx, 4, 64));
        float se = __expf(mlj - mx);
        se += __shfl_xor(se, 1, 64);
        se += __shfl_xor(se, 2, 64);
        se += __shfl_xor(se, 4, 64);
        const float lse = mx + __logf(se);
        if (j == (ck & 7)) off_g[ck] = mlj - lse - 58.8120661251f;
    }

    const float* Lsrc = L_g + (size_t)ck * D_ * D_;
#pragma unroll
    for (int t = 0; t < D_; ++t)
        Ls[t][j] = Lsrc[t * D_ + j];
    mus[j] = loc_g[ck * D_ + j];
    __syncthreads();

    // substitution: a[i] = -(sum_{m<i} L[i][m] a[m])  (unit diagonal)
    float a[D_];
#pragma unroll
    for (int m = 0; m < D_; ++m) a[m] = (j == m) ? 1.f : 0.f;

#pragma unroll
    for (int i = 1; i < D_; ++i) {
        float a0 = 0.f, a1 = 0.f, a2 = 0.f, a3 = 0.f;
#pragma unroll
        for (int m0 = 0; m0 + 3 < i; m0 += 4) {
            const float4 L4 = *reinterpret_cast<const float4*>(&Ls[i][m0]);
            a0 = fmaf(L4.x, a[m0 + 0], a0);
            a1 = fmaf(L4.y, a[m0 + 1], a1);
            a2 = fmaf(L4.z, a[m0 + 2], a2);
            a3 = fmaf(L4.w, a[m0 + 3], a3);
        }
#pragma unroll
        for (int m = i & ~3; m < i; ++m) a0 = fmaf(Ls[i][m], a[m], a0);
        const float nv = -((a0 + a1) + (a2 + a3));
        a[i] = (j < i) ? nv : a[i];
    }

#pragma unroll
    for (int m = 0; m < D_; ++m) At[m][j] = a[m];
    __syncthreads();

    // pack B-fragments + v from f16-rounded fragments
    const int q8 = (j >> 4) * 8, cl = j & 15;
    float vpart[4];
#pragma unroll
    for (int dt = 0; dt < 4; ++dt) {
        vpart[dt] = 0.f;
#pragma unroll
        for (int ks = 0; ks < 2; ++ks) {
            f16x8 t;
#pragma unroll
            for (int s = 0; s < 8; ++s) {
                const _Float16 h = (_Float16)At[dt * 16 + cl][ks * 32 + q8 + s];
                t[s] = h;
                vpart[dt] = fmaf((float)h, mus[ks * 32 + q8 + s], vpart[dt]);
            }
            ATf[(size_t)ck * 512 + (dt * 2 + ks) * 64 + j] = t;
        }
        vpart[dt] += __shfl_xor(vpart[dt], 16, 64);
        vpart[dt] += __shfl_xor(vpart[dt], 32, 64);
    }
    if (j < 16) {
#pragma unroll
        for (int dt = 0; dt < 4; ++dt)
            v_g[(size_t)ck * D_ + dt * 16 + j] = vpart[dt];
    }
}

// ---------------- kernel 2: MFMA GEMM + quad + LSE over K ---------------------------
// block: 256 thr (4 waves) = one class c x 128 b-rows; wave w handles components
// w and w+4 sequentially (Bf in registers per half). X tile (16 KB) staged once,
// xor-swizzled. No serial preamble: offsets are precomputed. LDS ~20.5 KB,
// VGPR ~100 -> 4 blocks/CU resident, 1600 blocks (6.25/CU) for convoy overlap.
__global__ __launch_bounds__(256, 4) void k_main(const _Float16* __restrict__ Xh,
                                                 const f16x8* __restrict__ ATf,
                                                 const float* __restrict__ v_g,
                                                 const float* __restrict__ off_g,
                                                 float* __restrict__ clp_g) {
    const int c = blockIdx.y;
    const int b0 = blockIdx.x * 128;
    const int tid = threadIdx.x;
    const int w = tid >> 6;
    const int lane = tid & 63;
    const int col = lane & 15;
    const int quad = lane >> 4;

    __shared__ f16x8 Xs[1024];       // 16 KB: subtile s in 0..3 (32 rows each)
    __shared__ float qk[K_][132];    // 4.2 KB
    __shared__ float offs_s[K_];

    if (tid < K_) offs_s[tid] = off_g[c * K_ + tid];

    // stage X tile: coalesced global f16x8 reads, xor-swizzled LDS writes
#pragma unroll
    for (int p = 0; p < 4; ++p) {
        const int u = p * 256 + tid;
        const int q = u & 7, row = u >> 3;
        const f16x8 val = *reinterpret_cast<const f16x8*>(
            Xh + (size_t)(b0 + row) * D_ + q * 8);
        const int s = row >> 5, bt = (row >> 4) & 1, cc = row & 15;
        Xs[((s * 2 + bt) * 8 + q) * 16 + (q ^ cc)] = val;
    }
    __syncthreads();

#pragma unroll 1
    for (int half = 0; half < 2; ++half) {
        const int k = w + half * 4;          // this wave's component
        const int ck = c * K_ + k;
        f16x8 Bf[8];
#pragma unroll
        for (int f = 0; f < 8; ++f)
            Bf[f] = ATf[(size_t)ck * 512 + f * 64 + lane];
        float vv[4];
#pragma unroll
        for (int dt = 0; dt < 4; ++dt)
            vv[dt] = v_g[(size_t)ck * D_ + dt * 16 + col];

#pragma unroll 1
        for (int s = 0; s < 4; ++s) {
            f16x8 Xf[2][2];
#pragma unroll
            for (int bt = 0; bt < 2; ++bt)
#pragma unroll
                for (int ks = 0; ks < 2; ++ks) {
                    const int q = ks * 4 + quad;
                    Xf[bt][ks] = Xs[((s * 2 + bt) * 8 + q) * 16 + (q ^ col)];
                }

            f32x4 acc[2][4];
#pragma unroll
            for (int bt = 0; bt < 2; ++bt)
#pragma unroll
                for (int dt = 0; dt < 4; ++dt) {
                    const f32x4 ini = {-vv[dt], -vv[dt], -vv[dt], -vv[dt]};
                    acc[bt][dt] = __builtin_amdgcn_mfma_f32_16x16x32_f16(
                        Xf[bt][0], Bf[dt * 2 + 0], ini, 0, 0, 0);
                    acc[bt][dt] = __builtin_amdgcn_mfma_f32_16x16x32_f16(
                        Xf[bt][1], Bf[dt * 2 + 1], acc[bt][dt], 0, 0, 0);
                }

#pragma unroll
            for (int bt = 0; bt < 2; ++bt) {
                float p[4];
#pragma unroll
                for (int r = 0; r < 4; ++r) {
                    float sum = 0.f;
#pragma unroll
                    for (int dt = 0; dt < 4; ++dt) {
                        const float y = acc[bt][dt][r];   // already z - v
                        sum = fmaf(y, y, sum);
                    }
                    p[r] = sum;
                }
#pragma unroll
                for (int r = 0; r < 4; ++r) p[r] = sum16(p[r]);
                if (col == 0) {
                    f32x4 pv = {p[0], p[1], p[2], p[3]};
                    *reinterpret_cast<f32x4*>(
                        &qk[k][s * 32 + bt * 16 + quad * 4]) = pv;
                }
            }
        }
    }
    __syncthreads();

    // LSE over k, one thread per row; coalesced clp[c][b] write.
    if (tid < 128) {
        float lp[K_];
        float m = -INFINITY;
#pragma unroll
        for (int k = 0; k < K_; ++k) {
            lp[k] = fmaf(-0.5f, qk[k][tid], offs_s[k]);
            m = fmaxf(m, lp[k]);
        }
        float s = 0.f;
#pragma unroll
        for (int k = 0; k < K_; ++k) s += __expf(lp[k] - m);
        clp_g[(size_t)c * B_ + b0 + tid] = m + __logf(s);
    }
}

// ---------------- kernel 3: log_softmax over C per batch row -------------------------
// clp layout is [C][B]; lane = class index.
__global__ __launch_bounds__(256) void k_final(const float* __restrict__ clp,
                                               float* __restrict__ out) {
    const int wave = threadIdx.x >> 6;
    const int lane = threadIdx.x & 63;
    const int b = blockIdx.x * 4 + wave;
    const float x0 = clp[(size_t)lane * B_ + b];
    const float x1 = (lane < C_ - 64) ? clp[(size_t)(64 + lane) * B_ + b] : -INFINITY;
    float m = fmaxf(x0, x1);
    for (int o = 32; o > 0; o >>= 1) m = fmaxf(m, __shfl_xor(m, o, 64));
    float s = __expf(x0 - m) + ((lane < C_ - 64) ? __expf(x1 - m) : 0.f);
    for (int o = 32; o > 0; o >>= 1) s += __shfl_xor(s, o, 64);
    const float L = m + __logf(s);
    out[(size_t)b * C_ + lane] = x0 - L;
    if (lane < C_ - 64) out[(size_t)b * C_ + 64 + lane] = x1 - L;
}

extern "C" void kernel_launch(void* const* d_in, const int* in_sizes, int n_in,
                              void* d_out, int out_size, void* d_ws, size_t ws_size,
                              hipStream_t stream) {
    const float* rep = (const float*)d_in[0];        // [B, D]
    const float* ml  = (const float*)d_in[1];        // [C, K]
    const float* loc = (const float*)d_in[2];        // [C, K, D]
    const float* st  = (const float*)d_in[3];        // [C, K, D, D]
    float* out = (float*)d_out;                      // [B, C]

    char* w = (char*)d_ws;
    f16x8*    ATf = (f16x8*)w;                        // 6,553,600 B
    _Float16* Xh  = (_Float16*)(w + 6553600);         // 262,144 B
    float*    v   = (float*)(w + 6815744);            // 204,800 B
    float*    off = (float*)(w + 7020544);            // 3,200 B
    float*    clp = (float*)(w + 7023744);            // 819,200 B  [C][B]

    k_invert<<<dim3(C_ * K_), dim3(64), 0, stream>>>(st, rep, loc, ml, ATf, Xh, v, off);
    k_main<<<dim3(B_ / 128, C_), dim3(256), 0, stream>>>(Xh, ATf, v, off, clp);
    k_final<<<dim3(B_ / 4), dim3(256), 0, stream>>>(clp, out);
}

// Round 9
// 100.567 us; speedup vs baseline: 1.9496x; 1.0200x over previous
//
#include <hip/hip_runtime.h>
#include <math.h>

#define C_ 100
#define K_ 8
#define D_ 64
#define B_ 2048

using f16x8 = __attribute__((ext_vector_type(8))) _Float16;
using f32x4 = __attribute__((ext_vector_type(4))) float;

// ---------------- kernel 1: invert unit-lower-triangular L per (c,k) ----------------
// Register-resident substitution (~132 VGPR -> must stay its own kernel; R6 proved
// fusing under an occupancy-bound launch spills a[64]). Unit diagonal by construction
// (tril(raw,-1)+eye): logdet==0, no divides. Per-(c,k) mixture offset computed here.
// X-cast removed (R9): k_main casts f32->f16 during its own staging.
#define LS_S 68
#define AT_S 65
__global__ __launch_bounds__(64, 1) void k_invert(const float* __restrict__ L_g,
                                                  const float* __restrict__ loc_g,
                                                  const float* __restrict__ ml,
                                                  f16x8* __restrict__ ATf,
                                                  float* __restrict__ v_g,
                                                  float* __restrict__ off_g) {
    const int ck = blockIdx.x;
    const int j = threadIdx.x;
    __shared__ float Ls[D_][LS_S];
    __shared__ float At[D_][AT_S];
    __shared__ float mus[D_];

    // per-(c,k) offset: off = ml[ck] - lse(ml[c,:]) - 0.5*D*log(2pi)
    {
        const int c8 = (ck >> 3) << 3;
        const float mlj = ml[c8 + (j & 7)];
        float mx = mlj;
        mx = fmaxf(mx, __shfl_xor(mx, 1, 64));
        mx = fmaxf(mx, __shfl_xor(mx, 2, 64));
        mx = fmaxf(mx, __shfl_xor(mx, 4, 64));
        float se = __expf(mlj - mx);
        se += __shfl_xor(se, 1, 64);
        se += __shfl_xor(se, 2, 64);
        se += __shfl_xor(se, 4, 64);
        const float lse = mx + __logf(se);
        if (j == (ck & 7)) off_g[ck] = mlj - lse - 58.8120661251f;
    }

    const float* Lsrc = L_g + (size_t)ck * D_ * D_;
#pragma unroll
    for (int t = 0; t < D_; ++t)
        Ls[t][j] = Lsrc[t * D_ + j];
    mus[j] = loc_g[ck * D_ + j];
    __syncthreads();

    // substitution: a[i] = -(sum_{m<i} L[i][m] a[m])  (unit diagonal)
    float a[D_];
#pragma unroll
    for (int m = 0; m < D_; ++m) a[m] = (j == m) ? 1.f : 0.f;

#pragma unroll
    for (int i = 1; i < D_; ++i) {
        float a0 = 0.f, a1 = 0.f, a2 = 0.f, a3 = 0.f;
#pragma unroll
        for (int m0 = 0; m0 + 3 < i; m0 += 4) {
            const float4 L4 = *reinterpret_cast<const float4*>(&Ls[i][m0]);
            a0 = fmaf(L4.x, a[m0 + 0], a0);
            a1 = fmaf(L4.y, a[m0 + 1], a1);
            a2 = fmaf(L4.z, a[m0 + 2], a2);
            a3 = fmaf(L4.w, a[m0 + 3], a3);
        }
#pragma unroll
        for (int m = i & ~3; m < i; ++m) a0 = fmaf(Ls[i][m], a[m], a0);
        const float nv = -((a0 + a1) + (a2 + a3));
        a[i] = (j < i) ? nv : a[i];
    }

#pragma unroll
    for (int m = 0; m < D_; ++m) At[m][j] = a[m];
    __syncthreads();

    // pack fragments (usable as MFMA A-operand over d-rows) + v from rounded frags
    const int q8 = (j >> 4) * 8, cl = j & 15;
    float vpart[4];
#pragma unroll
    for (int dt = 0; dt < 4; ++dt) {
        vpart[dt] = 0.f;
#pragma unroll
        for (int ks = 0; ks < 2; ++ks) {
            f16x8 t;
#pragma unroll
            for (int s = 0; s < 8; ++s) {
                const _Float16 h = (_Float16)At[dt * 16 + cl][ks * 32 + q8 + s];
                t[s] = h;
                vpart[dt] = fmaf((float)h, mus[ks * 32 + q8 + s], vpart[dt]);
            }
            ATf[(size_t)ck * 512 + (dt * 2 + ks) * 64 + j] = t;
        }
        vpart[dt] += __shfl_xor(vpart[dt], 16, 64);
        vpart[dt] += __shfl_xor(vpart[dt], 32, 64);
    }
    if (j < 16) {
#pragma unroll
        for (int dt = 0; dt < 4; ++dt)
            v_g[(size_t)ck * D_ + dt * 16 + j] = vpart[dt];
    }
}

// ---------------- kernel 2: MFMA GEMM + quad + LSE over K ---------------------------
// block: 256 thr (4 waves) = one class c x 128 b-rows; wave w handles components
// w and w+4. OPERAND-SWAPPED MFMA: D[i=d][j=b] (A-op = A-matrix frags, B-op = X
// frags — identical packing, just swapped call args). -v folds per-register into
// C-init; d-reduction = 16 in-lane FMAs + 2 shuffles (no DPP chains).
// Stages X directly from f32 rep (cast here; X is L2-resident).
__global__ __launch_bounds__(256, 4) void k_main(const float* __restrict__ rep,
                                                 const f16x8* __restrict__ ATf,
                                                 const float* __restrict__ v_g,
                                                 const float* __restrict__ off_g,
                                                 float* __restrict__ clp_g) {
    const int c = blockIdx.y;
    const int b0 = blockIdx.x * 128;
    const int tid = threadIdx.x;
    const int w = tid >> 6;
    const int lane = tid & 63;
    const int col = lane & 15;
    const int quad = lane >> 4;

    __shared__ f16x8 Xs[1024];       // 16 KB: 4 subtiles x 32 rows
    __shared__ float qk[K_][132];    // 4.2 KB
    __shared__ float offs_s[K_];

    if (tid < K_) offs_s[tid] = off_g[c * K_ + tid];

    // stage X tile: f32 global reads (coalesced 32B/thread), cast, swizzled LDS write
#pragma unroll
    for (int p = 0; p < 4; ++p) {
        const int u = p * 256 + tid;
        const int q = u & 7, row = u >> 3;
        const float* xr = rep + (size_t)(b0 + row) * D_ + q * 8;
        const float4 x0 = *reinterpret_cast<const float4*>(xr);
        const float4 x1 = *reinterpret_cast<const float4*>(xr + 4);
        f16x8 val;
        val[0] = (_Float16)x0.x; val[1] = (_Float16)x0.y;
        val[2] = (_Float16)x0.z; val[3] = (_Float16)x0.w;
        val[4] = (_Float16)x1.x; val[5] = (_Float16)x1.y;
        val[6] = (_Float16)x1.z; val[7] = (_Float16)x1.w;
        const int s = row >> 5, bt = (row >> 4) & 1, cc = row & 15;
        Xs[((s * 2 + bt) * 8 + q) * 16 + (q ^ cc)] = val;
    }
    __syncthreads();

#pragma unroll 1
    for (int half = 0; half < 2; ++half) {
        const int k = w + half * 4;          // this wave's component
        const int ck = c * K_ + k;
        f16x8 Af[8];                          // A-matrix fragments (A-operand)
#pragma unroll
        for (int f = 0; f < 8; ++f)
            Af[f] = ATf[(size_t)ck * 512 + f * 64 + lane];
        f32x4 vvn[4];                         // -v, per-register (d = dt*16+quad*4+r)
#pragma unroll
        for (int dt = 0; dt < 4; ++dt)
            vvn[dt] = -(*reinterpret_cast<const f32x4*>(
                v_g + (size_t)ck * D_ + dt * 16 + quad * 4));

#pragma unroll 1
        for (int s = 0; s < 4; ++s) {
            f16x8 Xf[2][2];                   // X fragments (B-operand), b = col
#pragma unroll
            for (int bt = 0; bt < 2; ++bt)
#pragma unroll
                for (int ks = 0; ks < 2; ++ks) {
                    const int q = ks * 4 + quad;
                    Xf[bt][ks] = Xs[((s * 2 + bt) * 8 + q) * 16 + (q ^ col)];
                }

            f32x4 acc[2][4];                  // D[i=d][j=b]: col=b, quad*4+r=d
#pragma unroll
            for (int bt = 0; bt < 2; ++bt)
#pragma unroll
                for (int dt = 0; dt < 4; ++dt) {
                    acc[bt][dt] = __builtin_amdgcn_mfma_f32_16x16x32_f16(
                        Af[dt * 2 + 0], Xf[bt][0], vvn[dt], 0, 0, 0);
                    acc[bt][dt] = __builtin_amdgcn_mfma_f32_16x16x32_f16(
                        Af[dt * 2 + 1], Xf[bt][1], acc[bt][dt], 0, 0, 0);
                }

            // quad[b]: in-lane sum over 16 d's, then 2 shuffles across quad groups
#pragma unroll
            for (int bt = 0; bt < 2; ++bt) {
                float p = 0.f;
#pragma unroll
                for (int dt = 0; dt < 4; ++dt)
#pragma unroll
                    for (int r = 0; r < 4; ++r)
                        p = fmaf(acc[bt][dt][r], acc[bt][dt][r], p);
                p += __shfl_xor(p, 16, 64);
                p += __shfl_xor(p, 32, 64);
                if (quad == 0)
                    qk[k][s * 32 + bt * 16 + col] = p;
            }
        }
    }
    __syncthreads();

    // LSE over k, one thread per row; coalesced clp[c][b] write.
    if (tid < 128) {
        float lp[K_];
        float m = -INFINITY;
#pragma unroll
        for (int k = 0; k < K_; ++k) {
            lp[k] = fmaf(-0.5f, qk[k][tid], offs_s[k]);
            m = fmaxf(m, lp[k]);
        }
        float s = 0.f;
#pragma unroll
        for (int k = 0; k < K_; ++k) s += __expf(lp[k] - m);
        clp_g[(size_t)c * B_ + b0 + tid] = m + __logf(s);
    }
}

// ---------------- kernel 3: log_softmax over C per batch row -------------------------
// clp layout is [C][B]; lane = class index.
__global__ __launch_bounds__(256) void k_final(const float* __restrict__ clp,
                                               float* __restrict__ out) {
    const int wave = threadIdx.x >> 6;
    const int lane = threadIdx.x & 63;
    const int b = blockIdx.x * 4 + wave;
    const float x0 = clp[(size_t)lane * B_ + b];
    const float x1 = (lane < C_ - 64) ? clp[(size_t)(64 + lane) * B_ + b] : -INFINITY;
    float m = fmaxf(x0, x1);
    for (int o = 32; o > 0; o >>= 1) m = fmaxf(m, __shfl_xor(m, o, 64));
    float s = __expf(x0 - m) + ((lane < C_ - 64) ? __expf(x1 - m) : 0.f);
    for (int o = 32; o > 0; o >>= 1) s += __shfl_xor(s, o, 64);
    const float L = m + __logf(s);
    out[(size_t)b * C_ + lane] = x0 - L;
    if (lane < C_ - 64) out[(size_t)b * C_ + 64 + lane] = x1 - L;
}

extern "C" void kernel_launch(void* const* d_in, const int* in_sizes, int n_in,
                              void* d_out, int out_size, void* d_ws, size_t ws_size,
                              hipStream_t stream) {
    const float* rep = (const float*)d_in[0];        // [B, D]
    const float* ml  = (const float*)d_in[1];        // [C, K]
    const float* loc = (const float*)d_in[2];        // [C, K, D]
    const float* st  = (const float*)d_in[3];        // [C, K, D, D]
    float* out = (float*)d_out;                      // [B, C]

    char* w = (char*)d_ws;
    f16x8* ATf = (f16x8*)w;                           // 6,553,600 B
    float* v   = (float*)(w + 6553600);               // 204,800 B
    float* off = (float*)(w + 6758400);               // 3,200 B
    float* clp = (float*)(w + 6761600);               // 819,200 B  [C][B]

    k_invert<<<dim3(C_ * K_), dim3(64), 0, stream>>>(st, loc, ml, ATf, v, off);
    k_main<<<dim3(B_ / 128, C_), dim3(256), 0, stream>>>(rep, ATf, v, off, clp);
    k_final<<<dim3(B_ / 4), dim3(256), 0, stream>>>(clp, out);
}